// Round 6
// baseline (1166.530 us; speedup 1.0000x reference)
//
#include <hip/hip_runtime.h>

#define RH 32
#define RT 2048
#define RC 10

typedef __attribute__((ext_vector_type(8))) _Float16 f16x8;
typedef __attribute__((ext_vector_type(4))) float f32x4;

#define MFMA16(a,b,c) __builtin_amdgcn_mfma_f32_16x16x32_f16((a),(b),(c),0,0,0)

// tanh(x) = 1 - 2/(exp(2x)+1); saturates correctly at +/-inf.
__device__ __forceinline__ float fast_tanh(float x) {
    float e = __builtin_amdgcn_exp2f(x * 2.88539008177792681472f);
    return fmaf(-2.0f, __builtin_amdgcn_rcpf(e + 1.0f), 1.0f);
}

// A-frag rows [base,base+16): lane(n,g) holds W[base+n][k], k = 4g+(e&3)+16*(e>>2)
// (layout validated end-to-end in rounds 4 and 5)
__device__ __forceinline__ f16x8 load_wfrag16(const float* __restrict__ W,
                                              int base, int n, int g) {
    f16x8 f;
#pragma unroll
    for (int e = 0; e < 8; ++e) {
        int k = 4*g + (e & 3) + 16*(e >> 2);
        f[e] = (_Float16)W[(base + n)*RH + k];   // RNE
    }
    return f;
}

__global__ __launch_bounds__(64) void rnn2_chain_kernel(
    const float* __restrict__ x,
    const float* __restrict__ W_ih0, const float* __restrict__ W_hh0,
    const float* __restrict__ b_ih0, const float* __restrict__ b_hh0,
    const float* __restrict__ W_ih1, const float* __restrict__ W_hh1,
    const float* __restrict__ b_ih1, const float* __restrict__ b_hh1,
    const float* __restrict__ fc_w, const float* __restrict__ fc_b,
    float* __restrict__ out)
{
    __shared__ float h2fin[16][RH];

    const int ln = threadIdx.x;      // single wave per block
    const int n  = ln & 15;          // batch column within 16-batch tile
    const int g  = ln >> 4;          // row/k 4-group

    // All 8 weight tile-fragments in registers (f16).
    f16x8 WI0a = load_wfrag16(W_ih0,  0, n, g);
    f16x8 WI0b = load_wfrag16(W_ih0, 16, n, g);
    f16x8 WH0a = load_wfrag16(W_hh0,  0, n, g);
    f16x8 WH0b = load_wfrag16(W_hh0, 16, n, g);
    f16x8 WI1a = load_wfrag16(W_ih1,  0, n, g);
    f16x8 WI1b = load_wfrag16(W_ih1, 16, n, g);
    f16x8 WH1a = load_wfrag16(W_hh1,  0, n, g);
    f16x8 WH1b = load_wfrag16(W_hh1, 16, n, g);

    f32x4 cb1a, cb1b, cb2a, cb2b;    // bias C-frags (rows 4g+i / 16+4g+i)
#pragma unroll
    for (int i = 0; i < 4; ++i) {
        cb1a[i] = b_ih0[4*g + i]      + b_hh0[4*g + i];
        cb1b[i] = b_ih0[16 + 4*g + i] + b_hh0[16 + 4*g + i];
        cb2a[i] = b_ih1[4*g + i]      + b_hh1[4*g + i];
        cb2b[i] = b_ih1[16 + 4*g + i] + b_hh1[16 + 4*g + i];
    }

    f16x8 h1f, h2f;                  // recurrent states (D-frag == next B-frag)
#pragma unroll
    for (int e = 0; e < 8; ++e) { h1f[e] = (_Float16)0.0f; h2f[e] = (_Float16)0.0f; }

    // x stream: lane (n,g) needs x[batch][t][4g..4g+3] and [16+4g..16+4g+3]
    const float* xp = x + (size_t)(blockIdx.x*16 + n) * (RT*RH) + 4*g;
    float4 A0, B0, A1, B1, A2, B2, A3, B3;   // 4-slot register prefetch ring

#define PREF(A_, B_, T_) do { \
    int tp_ = (T_) > (RT-1) ? (RT-1) : (T_); \
    const float* p_ = xp + (size_t)tp_ * RH; \
    A_ = *(const float4*)p_; \
    B_ = *(const float4*)(p_ + 16); \
} while (0)

#define CVTX(dst_, A_, B_) do { \
    auto q0_ = __builtin_amdgcn_cvt_pkrtz(A_.x, A_.y); \
    auto q1_ = __builtin_amdgcn_cvt_pkrtz(A_.z, A_.w); \
    auto q2_ = __builtin_amdgcn_cvt_pkrtz(B_.x, B_.y); \
    auto q3_ = __builtin_amdgcn_cvt_pkrtz(B_.z, B_.w); \
    dst_[0] = q0_[0]; dst_[1] = q0_[1]; dst_[2] = q1_[0]; dst_[3] = q1_[1]; \
    dst_[4] = q2_[0]; dst_[5] = q2_[1]; dst_[6] = q3_[0]; dst_[7] = q3_[1]; \
} while (0)

    // xacc = W_ih0 . x(t) + bias1, precomputed one step ahead (off-chain).
    f32x4 xacc0, xacc1;

    PREF(A0, B0, 0); PREF(A1, B1, 1); PREF(A2, B2, 2); PREF(A3, B3, 3);
    {
        f16x8 xf0; CVTX(xf0, A0, B0);
        xacc0 = MFMA16(WI0a, xf0, cb1a);
        xacc1 = MFMA16(WI0b, xf0, cb1b);
        PREF(A0, B0, 4);                      // slot 0 <- x(4)
    }

    // STEP at time T_: uses xacc (= f(x(T_))); ring slot regs SA_,SB_ hold
    // x(T_+1); refills that slot with x(T_+5) (clamped).
#define STEP(T_, SA_, SB_) do { \
    /* critical h1 cycle: ONE dependent MFMA */ \
    f32x4 d0_ = MFMA16(WH0a, h1f, xacc0); \
    f32x4 d1_ = MFMA16(WH0b, h1f, xacc1); \
    /* off-chain: build xacc for T_+1 */ \
    f16x8 xf_; CVTX(xf_, SA_, SB_); \
    PREF(SA_, SB_, (T_) + 5); \
    xacc0 = MFMA16(WI0a, xf_, cb1a); \
    xacc1 = MFMA16(WI0b, xf_, cb1b); \
    /* h1 tanh + pack (on-chain) */ \
    _Pragma("unroll") \
    for (int i_ = 0; i_ < 4; ++i_) { d0_[i_] = fast_tanh(d0_[i_]); d1_[i_] = fast_tanh(d1_[i_]); } \
    _Pragma("unroll") \
    for (int i_ = 0; i_ < 4; ++i_) { h1f[i_] = (_Float16)d0_[i_]; h1f[4+i_] = (_Float16)d1_[i_]; } \
    /* layer 2: own 1-MFMA recurrence cycle, slack of a full step */ \
    f32x4 e0_ = MFMA16(WI1a, h1f, cb2a); \
    f32x4 e1_ = MFMA16(WI1b, h1f, cb2b); \
    e0_ = MFMA16(WH1a, h2f, e0_); \
    e1_ = MFMA16(WH1b, h2f, e1_); \
    _Pragma("unroll") \
    for (int i_ = 0; i_ < 4; ++i_) { e0_[i_] = fast_tanh(e0_[i_]); e1_[i_] = fast_tanh(e1_[i_]); } \
    _Pragma("unroll") \
    for (int i_ = 0; i_ < 4; ++i_) { h2f[i_] = (_Float16)e0_[i_]; h2f[4+i_] = (_Float16)e1_[i_]; } \
} while (0)

    for (int k = 0; k < 512; ++k) {
        const int tb = 4*k;
        STEP(tb + 0, A1, B1);   // uses x(t+1) from slot (t+1)&3
        STEP(tb + 1, A2, B2);
        STEP(tb + 2, A3, B3);
        STEP(tb + 3, A0, B0);
    }
#undef STEP
#undef CVTX
#undef PREF

    // Final h2 -> LDS (f32), then FC epilogue across all 64 lanes.
#pragma unroll
    for (int i = 0; i < 4; ++i) {
        h2fin[n][4*g + i]      = (float)h2f[i];
        h2fin[n][16 + 4*g + i] = (float)h2f[4 + i];
    }
    __syncthreads();

    for (int c = ln; c < 16 * RC; c += 64) {
        const int bt = c / RC;
        const int cl = c % RC;
        float s = fc_b[cl];
#pragma unroll
        for (int kk = 0; kk < RH; ++kk)
            s = fmaf(fc_w[cl*RH + kk], h2fin[bt][kk], s);
        out[(size_t)(blockIdx.x*16 + bt) * RC + cl] = s;
    }
}

extern "C" void kernel_launch(void* const* d_in, const int* in_sizes, int n_in,
                              void* d_out, int out_size, void* d_ws, size_t ws_size,
                              hipStream_t stream) {
    const float* x     = (const float*)d_in[0];
    const float* W_ih0 = (const float*)d_in[1];
    const float* W_hh0 = (const float*)d_in[2];
    const float* b_ih0 = (const float*)d_in[3];
    const float* b_hh0 = (const float*)d_in[4];
    const float* W_ih1 = (const float*)d_in[5];
    const float* W_hh1 = (const float*)d_in[6];
    const float* b_ih1 = (const float*)d_in[7];
    const float* b_hh1 = (const float*)d_in[8];
    const float* fc_w  = (const float*)d_in[9];
    const float* fc_b  = (const float*)d_in[10];
    float* out = (float*)d_out;

    rnn2_chain_kernel<<<32, 64, 0, stream>>>(x, W_ih0, W_hh0, b_ih0, b_hh0,
                                             W_ih1, W_hh1, b_ih1, b_hh1,
                                             fc_w, fc_b, out);
}

// Round 7
// 629.077 us; speedup vs baseline: 1.8544x; 1.8544x over previous
//
#include <hip/hip_runtime.h>

#define RH 32
#define RT 2048
#define RC 10

typedef __attribute__((ext_vector_type(8))) _Float16 f16x8;
typedef __attribute__((ext_vector_type(4))) float f32x4;

#define MFMA16(a,b,c) __builtin_amdgcn_mfma_f32_16x16x32_f16((a),(b),(c),0,0,0)

// tanh(x) = 1 - 2/(exp(2x)+1); saturates correctly at +/-inf.
__device__ __forceinline__ float fast_tanh(float x) {
    float e = __builtin_amdgcn_exp2f(x * 2.88539008177792681472f);
    return fmaf(-2.0f, __builtin_amdgcn_rcpf(e + 1.0f), 1.0f);
}

// A-frag rows [base,base+16): lane(n,g) holds W[base+n][k], k = 4g+(e&3)+16*(e>>2)
// (layout validated end-to-end in rounds 4 and 5)
__device__ __forceinline__ f16x8 load_wfrag16(const float* __restrict__ W,
                                              int base, int n, int g) {
    f16x8 f;
#pragma unroll
    for (int e = 0; e < 8; ++e) {
        int k = 4*g + (e & 3) + 16*(e >> 2);
        f[e] = (_Float16)W[(base + n)*RH + k];   // RNE
    }
    return f;
}

__global__ __launch_bounds__(64) void rnn2_stag_kernel(
    const float* __restrict__ x,
    const float* __restrict__ W_ih0, const float* __restrict__ W_hh0,
    const float* __restrict__ b_ih0, const float* __restrict__ b_hh0,
    const float* __restrict__ W_ih1, const float* __restrict__ W_hh1,
    const float* __restrict__ b_ih1, const float* __restrict__ b_hh1,
    const float* __restrict__ fc_w, const float* __restrict__ fc_b,
    float* __restrict__ out)
{
    __shared__ float h2fin[16][RH];

    const int ln = threadIdx.x;      // single wave per block
    const int n  = ln & 15;          // batch column within 16-batch tile
    const int g  = ln >> 4;          // row/k 4-group

    // All 8 weight tile-fragments in registers (f16).
    f16x8 WI0a = load_wfrag16(W_ih0,  0, n, g);
    f16x8 WI0b = load_wfrag16(W_ih0, 16, n, g);
    f16x8 WH0a = load_wfrag16(W_hh0,  0, n, g);
    f16x8 WH0b = load_wfrag16(W_hh0, 16, n, g);
    f16x8 WI1a = load_wfrag16(W_ih1,  0, n, g);
    f16x8 WI1b = load_wfrag16(W_ih1, 16, n, g);
    f16x8 WH1a = load_wfrag16(W_hh1,  0, n, g);
    f16x8 WH1b = load_wfrag16(W_hh1, 16, n, g);

    f32x4 cb1a, cb1b, cb2a, cb2b;    // bias C-frags (rows 4g+i / 16+4g+i)
#pragma unroll
    for (int i = 0; i < 4; ++i) {
        cb1a[i] = b_ih0[4*g + i]      + b_hh0[4*g + i];
        cb1b[i] = b_ih0[16 + 4*g + i] + b_hh0[16 + 4*g + i];
        cb2a[i] = b_ih1[4*g + i]      + b_hh1[4*g + i];
        cb2b[i] = b_ih1[16 + 4*g + i] + b_hh1[16 + 4*g + i];
    }

    f16x8 h1f, h2f;                  // recurrent states (D-frag == next B-frag)
#pragma unroll
    for (int e = 0; e < 8; ++e) { h1f[e] = (_Float16)0.0f; h2f[e] = (_Float16)0.0f; }

    // x stream: lane (n,g) needs x[batch][t][4g..4g+3] and [16+4g..16+4g+3]
    const float* xp = x + (size_t)(blockIdx.x*16 + n) * (RT*RH) + 4*g;
    float4 A0, B0, A1, B1, A2, B2, A3, B3;   // 4-slot register prefetch ring

#define PREF(A_, B_, T_) do { \
    const float* p_ = xp + (size_t)(T_) * RH; \
    A_ = *(const float4*)p_; \
    B_ = *(const float4*)(p_ + 16); \
} while (0)

#define CVTX(dst_, A_, B_) do { \
    auto q0_ = __builtin_amdgcn_cvt_pkrtz(A_.x, A_.y); \
    auto q1_ = __builtin_amdgcn_cvt_pkrtz(A_.z, A_.w); \
    auto q2_ = __builtin_amdgcn_cvt_pkrtz(B_.x, B_.y); \
    auto q3_ = __builtin_amdgcn_cvt_pkrtz(B_.z, B_.w); \
    dst_[0] = q0_[0]; dst_[1] = q0_[1]; dst_[2] = q1_[0]; dst_[3] = q1_[1]; \
    dst_[4] = q2_[0]; dst_[5] = q2_[1]; dst_[6] = q3_[0]; dst_[7] = q3_[1]; \
} while (0)

    // Staggered step at time T_: L1 makes h1(T_) from h1f=h1(T_-1);
    // L2 makes h2(T_-1) from the SAME pre-update h1f and h2f=h2(T_-2).
    // Both recurrent chains run in parallel; h1f/h2f overwritten at end.
#define STEP(T_, SA_, SB_, DOPREF) do { \
    f16x8 xf_; CVTX(xf_, SA_, SB_); \
    /* first-stage MFMAs: all operands ready at step start */ \
    f32x4 e0_ = MFMA16(WI1a, h1f, cb2a); \
    f32x4 e1_ = MFMA16(WI1b, h1f, cb2b); \
    f32x4 d0_ = MFMA16(WI0a, xf_, cb1a); \
    f32x4 d1_ = MFMA16(WI0b, xf_, cb1b); \
    /* second-stage (recurrent) MFMAs */ \
    e0_ = MFMA16(WH1a, h2f, e0_); \
    e1_ = MFMA16(WH1b, h2f, e1_); \
    d0_ = MFMA16(WH0a, h1f, d0_); \
    d1_ = MFMA16(WH0b, h1f, d1_); \
    if (DOPREF) { PREF(SA_, SB_, (T_) + 4); } \
    _Pragma("unroll") \
    for (int i_ = 0; i_ < 4; ++i_) { e0_[i_] = fast_tanh(e0_[i_]); e1_[i_] = fast_tanh(e1_[i_]); } \
    _Pragma("unroll") \
    for (int i_ = 0; i_ < 4; ++i_) { h2f[i_] = (_Float16)e0_[i_]; h2f[4+i_] = (_Float16)e1_[i_]; } \
    _Pragma("unroll") \
    for (int i_ = 0; i_ < 4; ++i_) { d0_[i_] = fast_tanh(d0_[i_]); d1_[i_] = fast_tanh(d1_[i_]); } \
    _Pragma("unroll") \
    for (int i_ = 0; i_ < 4; ++i_) { h1f[i_] = (_Float16)d0_[i_]; h1f[4+i_] = (_Float16)d1_[i_]; } \
} while (0)

    PREF(A0, B0, 0); PREF(A1, B1, 1); PREF(A2, B2, 2); PREF(A3, B3, 3);

    {   // prologue t=0, layer-1 only (WH0*0 == 0 exactly, skipped)
        f16x8 xf0; CVTX(xf0, A0, B0);
        f32x4 d0_ = MFMA16(WI0a, xf0, cb1a);
        f32x4 d1_ = MFMA16(WI0b, xf0, cb1b);
        PREF(A0, B0, 4);
#pragma unroll
        for (int i = 0; i < 4; ++i) { d0_[i] = fast_tanh(d0_[i]); d1_[i] = fast_tanh(d1_[i]); }
#pragma unroll
        for (int i = 0; i < 4; ++i) { h1f[i] = (_Float16)d0_[i]; h1f[4+i] = (_Float16)d1_[i]; }
    }

    for (int k = 0; k < 510; ++k) {      // staggered t = 1 .. 2040
        const int tb = 4*k;
        STEP(tb + 1, A1, B1, 1);
        STEP(tb + 2, A2, B2, 1);
        STEP(tb + 3, A3, B3, 1);
        STEP(tb + 4, A0, B0, 1);
    }
    // peeled iter: t = 2041..2044 (prefetch x2045..x2047; none for slot 0)
    STEP(2041, A1, B1, 1);
    STEP(2042, A2, B2, 1);
    STEP(2043, A3, B3, 1);
    STEP(2044, A0, B0, 0);
    // tail: t = 2045..2047, no prefetch
    STEP(2045, A1, B1, 0);
    STEP(2046, A2, B2, 0);
    STEP(2047, A3, B3, 0);

    {   // final layer-2-only step: h2(2047) from h1(2047), h2(2046)
        f32x4 e0_ = MFMA16(WI1a, h1f, cb2a);
        f32x4 e1_ = MFMA16(WI1b, h1f, cb2b);
        e0_ = MFMA16(WH1a, h2f, e0_);
        e1_ = MFMA16(WH1b, h2f, e1_);
#pragma unroll
        for (int i = 0; i < 4; ++i) { e0_[i] = fast_tanh(e0_[i]); e1_[i] = fast_tanh(e1_[i]); }
#pragma unroll
        for (int i = 0; i < 4; ++i) {
            h2fin[n][4*g + i]      = e0_[i];
            h2fin[n][16 + 4*g + i] = e1_[i];
        }
    }
#undef STEP
#undef CVTX
#undef PREF

    __syncthreads();

    for (int c = ln; c < 16 * RC; c += 64) {
        const int bt = c / RC;
        const int cl = c % RC;
        float s = fc_b[cl];
#pragma unroll
        for (int kk = 0; kk < RH; ++kk)
            s = fmaf(fc_w[cl*RH + kk], h2fin[bt][kk], s);
        out[(size_t)(blockIdx.x*16 + bt) * RC + cl] = s;
    }
}

extern "C" void kernel_launch(void* const* d_in, const int* in_sizes, int n_in,
                              void* d_out, int out_size, void* d_ws, size_t ws_size,
                              hipStream_t stream) {
    const float* x     = (const float*)d_in[0];
    const float* W_ih0 = (const float*)d_in[1];
    const float* W_hh0 = (const float*)d_in[2];
    const float* b_ih0 = (const float*)d_in[3];
    const float* b_hh0 = (const float*)d_in[4];
    const float* W_ih1 = (const float*)d_in[5];
    const float* W_hh1 = (const float*)d_in[6];
    const float* b_ih1 = (const float*)d_in[7];
    const float* b_hh1 = (const float*)d_in[8];
    const float* fc_w  = (const float*)d_in[9];
    const float* fc_b  = (const float*)d_in[10];
    float* out = (float*)d_out;

    rnn2_stag_kernel<<<32, 64, 0, stream>>>(x, W_ih0, W_hh0, b_ih0, b_hh0,
                                            W_ih1, W_hh1, b_ih1, b_hh1,
                                            fc_w, fc_b, out);
}